// Round 3
// baseline (11676.508 us; speedup 1.0000x reference)
//
#include <hip/hip_runtime.h>
#include <math.h>

// Problem constants (match reference file)
#define BATCH 4
#define NPTS 16384
#define M 4096          // centers per cloud = RATIO * NPTS
#define MAX_NB 64
#define R2F 0.0625f     // R*R = 0.25*0.25 (exactly representable)
#define FPS_T 512       // threads per FPS block
#define PPT 32          // points per thread = NPTS / FPS_T

// ---------------------------------------------------------------------------
// Semantics (B): XLA-fused scan-body rounding. The reference's _fps runs
// inside jax.lax.scan (always XLA-compiled+fused): sum((a-b)**2, axis=-1)
// becomes a contracted fma chain acc = fma(d_i, d_i, acc) over the 6 dims,
// f32 throughout. __builtin_fmaf is immune to compiler fp flags.
// ---------------------------------------------------------------------------
__device__ __forceinline__ float dist2_fma(
    float a0, float a1, float a2, float a3, float a4, float a5,
    float b0, float b1, float b2, float b3, float b4, float b5) {
  float d0 = a0 - b0;
  float s = __builtin_fmaf(d0, d0, 0.0f);   // == round(d0*d0), XLA init acc=0
  float d1 = a1 - b1; s = __builtin_fmaf(d1, d1, s);
  float d2 = a2 - b2; s = __builtin_fmaf(d2, d2, s);
  float d3 = a3 - b3; s = __builtin_fmaf(d3, d3, s);
  float d4 = a4 - b4; s = __builtin_fmaf(d4, d4, s);
  float d5 = a5 - b5; s = __builtin_fmaf(d5, d5, s);
  return s;
}

// ---------------------------------------------------------------------------
// Semantics (A): op-by-op numpy/jnp rounding for the neighbor phase (the
// reference's python b-loop runs uncompiled): squares materialized, then a
// sequential sum. Contraction pinned off (HIP default is contract=fast).
// ---------------------------------------------------------------------------
__device__ __forceinline__ float dist2_seq(
    float a0, float a1, float a2, float a3, float a4, float a5,
    float b0, float b1, float b2, float b3, float b4, float b5) {
#pragma clang fp contract(off)
  float d0 = a0 - b0; float s = d0 * d0;
  float d1 = a1 - b1; s = s + d1 * d1;
  float d2 = a2 - b2; s = s + d2 * d2;
  float d3 = a3 - b3; s = s + d3 * d3;
  float d4 = a4 - b4; s = s + d4 * d4;
  float d5 = a5 - b5; s = s + d5 * d5;
  return s;
}

// ---------------------------------------------------------------------------
// Kernel 1: farthest point sampling, one block per cloud. 512 threads x 32
// interleaved points (p = j*512 + t). ALL per-point state in registers:
// 6 f32 coords + f32 mind = 224 VGPRs (fits the launch_bounds(512,2) 256
// cap). LDS is only the 72 B cross-wave argmax scratch. Per pick: fma-chain
// distance to the new center, min-update, block argmax (first-index ties).
// ---------------------------------------------------------------------------
__global__ __launch_bounds__(FPS_T, 2) void fps_kernel(
    const float* __restrict__ x, const float* __restrict__ pos,
    float* __restrict__ out) {
  __shared__ float s_rv[FPS_T / 64];
  __shared__ int s_ri[FPS_T / 64];
  __shared__ int s_g;

  const int b = blockIdx.x;
  const int t = threadIdx.x;
  const float* xb = x + (size_t)b * NPTS * 3;
  const float* pb = pos + (size_t)b * NPTS * 3;

  float* out_pos = out + (size_t)BATCH * M * 3;              // second output
  int* idx_stash = (int*)(out + (size_t)2 * BATCH * M * 3);  // batch region

  // My 32 points' 6-D coords + mind, all registers.
  float c0[PPT], c1[PPT], c2[PPT], c3[PPT], c4[PPT], c5[PPT], mind[PPT];
#pragma unroll
  for (int j = 0; j < PPT; ++j) {
    const int p = j * FPS_T + t;
    c0[j] = xb[3 * p + 0];
    c1[j] = xb[3 * p + 1];
    c2[j] = xb[3 * p + 2];
    c3[j] = pb[3 * p + 0];
    c4[j] = pb[3 * p + 1];
    c5[j] = pb[3 * p + 2];
    mind[j] = INFINITY;  // minimum(inf, d) == d on the first iteration
  }

  int g = 0;  // current pick (local index); ref starts at 0
  for (int k = 0; k < M; ++k) {
    const float fx0 = xb[3 * g + 0];
    const float fx1 = xb[3 * g + 1];
    const float fx2 = xb[3 * g + 2];
    const float fx3 = pb[3 * g + 0];
    const float fx4 = pb[3 * g + 1];
    const float fx5 = pb[3 * g + 2];

    if (t == 0) {
      idx_stash[b * M + k] = g;                    // for kernel 2
      out_pos[(size_t)(b * M + k) * 3 + 0] = fx3;  // pos[idx_g] (exact copy)
      out_pos[(size_t)(b * M + k) * 3 + 1] = fx4;
      out_pos[(size_t)(b * M + k) * 3 + 2] = fx5;
    }
    if (k == M - 1) break;  // last pick needs no further update/argmax

    // Min-update + per-thread (max, first-index). p ascending in j, so
    // strict > keeps the earliest index within this thread.
    float bestv = -1.0f;  // minds are >= 0
    int besti = 0;
#pragma unroll
    for (int j = 0; j < PPT; ++j) {
      const float d2 = dist2_fma(c0[j], c1[j], c2[j], c3[j], c4[j], c5[j],
                                 fx0, fx1, fx2, fx3, fx4, fx5);
      const float nm = fminf(mind[j], d2);  // == jnp.minimum (no NaNs)
      mind[j] = nm;
      if (nm > bestv) {
        bestv = nm;
        besti = j * FPS_T + t;
      }
    }

    // Wave-level argmax reduce, tie -> smaller index (assoc+comm merge).
#pragma unroll
    for (int off = 32; off > 0; off >>= 1) {
      const float ov = __shfl_xor(bestv, off, 64);
      const int oi = __shfl_xor(besti, off, 64);
      if (ov > bestv || (ov == bestv && oi < besti)) {
        bestv = ov;
        besti = oi;
      }
    }
    const int w = t >> 6;
    if ((t & 63) == 0) {
      s_rv[w] = bestv;
      s_ri[w] = besti;
    }
    __syncthreads();
    if (t == 0) {
      float bv = s_rv[0];
      int bi = s_ri[0];
#pragma unroll
      for (int ww = 1; ww < FPS_T / 64; ++ww) {
        const float v = s_rv[ww];
        const int i2 = s_ri[ww];
        if (v > bv || (v == bv && i2 < bi)) {
          bv = v;
          bi = i2;
        }
      }
      s_g = bi;
    }
    __syncthreads();
    g = s_g;
  }
}

// ---------------------------------------------------------------------------
// Kernel 2: radius-neighbor capped mean. One wave per 4 centers. Membership
// in f32 sequential-no-fma (op-by-op reference semantics); feature sums f32
// (order noise ~1e-6 << 6e-2 threshold). count > 64: exact ordered
// first-64-by-index re-scan (wave-uniform, rare at lambda~15).
// ---------------------------------------------------------------------------
#define K2_T 256
__global__ __launch_bounds__(K2_T, 4) void nbr_kernel(
    const float* __restrict__ x, const float* __restrict__ pos,
    float* __restrict__ out) {
  const int lane = threadIdx.x & 63;
  const int w = threadIdx.x >> 6;
  const int cbase = blockIdx.x * 16 + w * 4;  // 4 centers per wave

  const int* idx_stash = (const int*)(out + (size_t)2 * BATCH * M * 3);
  float* out_x = out;
  float* out_batch = out + (size_t)2 * BATCH * M * 3;

  const int b = cbase / M;  // all 16 centers of a block share a cloud
  const float* xb = x + (size_t)b * NPTS * 3;
  const float* pb = pos + (size_t)b * NPTS * 3;

  float cc0[4], cc1[4], cc2[4], cc3[4], cc4[4], cc5[4];
#pragma unroll
  for (int i = 0; i < 4; ++i) {
    const int c = idx_stash[cbase + i];  // local index within cloud
    cc0[i] = xb[3 * c + 0];
    cc1[i] = xb[3 * c + 1];
    cc2[i] = xb[3 * c + 2];
    cc3[i] = pb[3 * c + 0];
    cc4[i] = pb[3 * c + 1];
    cc5[i] = pb[3 * c + 2];
  }

  float s0[4] = {0, 0, 0, 0}, s1[4] = {0, 0, 0, 0}, s2[4] = {0, 0, 0, 0};
  int cnt[4] = {0, 0, 0, 0};

  for (int p = lane; p < NPTS; p += 64) {
    const float x0 = xb[3 * p + 0];
    const float x1 = xb[3 * p + 1];
    const float x2 = xb[3 * p + 2];
    const float q0 = pb[3 * p + 0];
    const float q1 = pb[3 * p + 1];
    const float q2 = pb[3 * p + 2];
#pragma unroll
    for (int i = 0; i < 4; ++i) {
      const float d2 = dist2_seq(cc0[i], cc1[i], cc2[i], cc3[i], cc4[i],
                                 cc5[i], x0, x1, x2, q0, q1, q2);
      if (d2 <= R2F) {
        cnt[i] += 1;
        s0[i] += x0;
        s1[i] += x1;
        s2[i] += x2;
      }
    }
  }

  // Wave reductions (sum); all lanes end with totals.
#pragma unroll
  for (int i = 0; i < 4; ++i) {
#pragma unroll
    for (int off = 32; off > 0; off >>= 1) {
      s0[i] += __shfl_xor(s0[i], off, 64);
      s1[i] += __shfl_xor(s1[i], off, 64);
      s2[i] += __shfl_xor(s2[i], off, 64);
      cnt[i] += __shfl_xor(cnt[i], off, 64);
    }
  }

#pragma unroll
  for (int i = 0; i < 4; ++i) {
    const int total = cnt[i];
    float m0, m1, m2;
    if (total <= MAX_NB) {
      const float denom = (float)total;  // >= 1 (self is always in range)
      m0 = s0[i] / denom;
      m1 = s1[i] / denom;
      m2 = s2[i] / denom;
    } else {
      // Exact first-64-by-index fallback (wave-uniform branch, rare).
      const int base = lane * (NPTS / 64);
      int lc = 0;
      for (int p = base; p < base + NPTS / 64; ++p) {
        const float d2 =
            dist2_seq(cc0[i], cc1[i], cc2[i], cc3[i], cc4[i], cc5[i],
                      xb[3 * p + 0], xb[3 * p + 1], xb[3 * p + 2],
                      pb[3 * p + 0], pb[3 * p + 1], pb[3 * p + 2]);
        if (d2 <= R2F) lc += 1;
      }
      int pre = 0;
      for (int l = 0; l < 64; ++l) {
        const int c = __shfl(lc, l, 64);
        if (l < lane) pre += c;
      }
      float t0 = 0, t1 = 0, t2 = 0;
      int r = pre;
      for (int p = base; p < base + NPTS / 64; ++p) {
        const float x0 = xb[3 * p + 0], x1 = xb[3 * p + 1],
                    x2 = xb[3 * p + 2];
        const float d2 =
            dist2_seq(cc0[i], cc1[i], cc2[i], cc3[i], cc4[i], cc5[i], x0, x1,
                      x2, pb[3 * p + 0], pb[3 * p + 1], pb[3 * p + 2]);
        if (d2 <= R2F) {
          if (r < MAX_NB) {
            t0 += x0;
            t1 += x1;
            t2 += x2;
          }
          r += 1;
        }
      }
#pragma unroll
      for (int off = 32; off > 0; off >>= 1) {
        t0 += __shfl_xor(t0, off, 64);
        t1 += __shfl_xor(t1, off, 64);
        t2 += __shfl_xor(t2, off, 64);
      }
      m0 = t0 / 64.0f;
      m1 = t1 / 64.0f;
      m2 = t2 / 64.0f;
    }
    if (lane == i) {
      const int gc = cbase + i;
      out_x[(size_t)gc * 3 + 0] = m0;
      out_x[(size_t)gc * 3 + 1] = m1;
      out_x[(size_t)gc * 3 + 2] = m2;
      out_batch[gc] = (float)b;  // batch ids as float in the float32 buffer
    }
  }
}

extern "C" void kernel_launch(void* const* d_in, const int* in_sizes, int n_in,
                              void* d_out, int out_size, void* d_ws,
                              size_t ws_size, hipStream_t stream) {
  (void)in_sizes;
  (void)n_in;
  (void)out_size;
  (void)d_ws;
  (void)ws_size;
  const float* x = (const float*)d_in[0];
  const float* pos = (const float*)d_in[1];
  // d_in[2] (batch) is implied by the contiguous equal-size layout.
  float* out = (float*)d_out;

  fps_kernel<<<BATCH, FPS_T, 0, stream>>>(x, pos, out);
  nbr_kernel<<<(BATCH * M) / 16, K2_T, 0, stream>>>(x, pos, out);
}

// Round 4
// 9461.822 us; speedup vs baseline: 1.2341x; 1.2341x over previous
//
#include <hip/hip_runtime.h>
#include <math.h>

// Problem constants (match reference file)
#define BATCH 4
#define NPTS 16384
#define M 4096          // centers per cloud = RATIO * NPTS
#define MAX_NB 64
#define R2F 0.0625f     // R*R = 0.25*0.25 (exactly representable)
#define FPS_T 512       // threads per FPS block
#define PPT 32          // points per thread = NPTS / FPS_T

// ---------------------------------------------------------------------------
// Semantics (B): XLA-fused scan-body rounding (verified bit-exact in R3).
// sum((a-b)**2) as a contracted fma chain, f32. __builtin_fmaf is immune to
// compiler fp flags.
// ---------------------------------------------------------------------------
__device__ __forceinline__ float dist2_fma(
    float a0, float a1, float a2, float a3, float a4, float a5,
    float b0, float b1, float b2, float b3, float b4, float b5) {
  float d0 = a0 - b0;
  float s = __builtin_fmaf(d0, d0, 0.0f);
  float d1 = a1 - b1; s = __builtin_fmaf(d1, d1, s);
  float d2 = a2 - b2; s = __builtin_fmaf(d2, d2, s);
  float d3 = a3 - b3; s = __builtin_fmaf(d3, d3, s);
  float d4 = a4 - b4; s = __builtin_fmaf(d4, d4, s);
  float d5 = a5 - b5; s = __builtin_fmaf(d5, d5, s);
  return s;
}

// Semantics (A): op-by-op numpy/jnp rounding for the neighbor phase
// (reference's python b-loop, uncompiled ops). Contraction pinned off.
__device__ __forceinline__ float dist2_seq(
    float a0, float a1, float a2, float a3, float a4, float a5,
    float b0, float b1, float b2, float b3, float b4, float b5) {
#pragma clang fp contract(off)
  float d0 = a0 - b0; float s = d0 * d0;
  float d1 = a1 - b1; s = s + d1 * d1;
  float d2 = a2 - b2; s = s + d2 * d2;
  float d3 = a3 - b3; s = s + d3 * d3;
  float d4 = a4 - b4; s = s + d4 * d4;
  float d5 = a5 - b5; s = s + d5 * d5;
  return s;
}

// ---------------------------------------------------------------------------
// Kernel 1: FPS, one block per cloud, 512 thr x 32 interleaved points, all
// per-point state (6 coords + mind = 224 f32) in registers.
// R3 post-mortem: launch_bounds(512,2) alone let the backend target 4
// waves/SIMD -> VGPR_Count=128 -> arrays spilled to scratch -> 830 MB HBM
// scratch traffic/dispatch. amdgpu_waves_per_eu(2,2) pins occupancy at 2
// waves/EU so the allocator gets the full 256-VGPR budget. Only 4 blocks
// exist (1/cloud); occupancy beyond 2 waves/EU is worthless anyway.
// ---------------------------------------------------------------------------
__global__
__attribute__((amdgpu_flat_work_group_size(FPS_T, FPS_T)))
__attribute__((amdgpu_waves_per_eu(2, 2)))
void fps_kernel(
    const float* __restrict__ x, const float* __restrict__ pos,
    float* __restrict__ out) {
  __shared__ float s_rv[FPS_T / 64];
  __shared__ int s_ri[FPS_T / 64];
  __shared__ int s_g;

  const int b = blockIdx.x;
  const int t = threadIdx.x;
  const float* xb = x + (size_t)b * NPTS * 3;
  const float* pb = pos + (size_t)b * NPTS * 3;

  float* out_pos = out + (size_t)BATCH * M * 3;              // second output
  int* idx_stash = (int*)(out + (size_t)2 * BATCH * M * 3);  // batch region

  // My 32 points' 6-D coords + mind, all registers.
  float c0[PPT], c1[PPT], c2[PPT], c3[PPT], c4[PPT], c5[PPT], mind[PPT];
#pragma unroll
  for (int j = 0; j < PPT; ++j) {
    const int p = j * FPS_T + t;
    c0[j] = xb[3 * p + 0];
    c1[j] = xb[3 * p + 1];
    c2[j] = xb[3 * p + 2];
    c3[j] = pb[3 * p + 0];
    c4[j] = pb[3 * p + 1];
    c5[j] = pb[3 * p + 2];
    mind[j] = INFINITY;  // minimum(inf, d) == d on the first pick
  }

  int g = 0;  // current pick (uniform; kept scalar via readfirstlane below)
  for (int k = 0; k < M; ++k) {
    // g is wave-uniform -> scalar center loads (frees VGPR address math).
    const float fx0 = xb[3 * g + 0];
    const float fx1 = xb[3 * g + 1];
    const float fx2 = xb[3 * g + 2];
    const float fx3 = pb[3 * g + 0];
    const float fx4 = pb[3 * g + 1];
    const float fx5 = pb[3 * g + 2];

    if (t == 0) {
      idx_stash[b * M + k] = g;                    // for kernel 2
      out_pos[(size_t)(b * M + k) * 3 + 0] = fx3;  // pos[idx_g] (exact copy)
      out_pos[(size_t)(b * M + k) * 3 + 1] = fx4;
      out_pos[(size_t)(b * M + k) * 3 + 2] = fx5;
    }
    if (k == M - 1) break;  // last pick needs no further update/argmax

    // Min-update + per-thread (max, first-j). j ascending => p ascending, so
    // strict > keeps the earliest original index within this thread.
    float bestv = -1.0f;  // minds are >= 0
    int bestj = 0;        // inline-const cndmask (cheaper than full index)
#pragma unroll
    for (int j = 0; j < PPT; ++j) {
      const float d2 = dist2_fma(c0[j], c1[j], c2[j], c3[j], c4[j], c5[j],
                                 fx0, fx1, fx2, fx3, fx4, fx5);
      const float nm = fminf(mind[j], d2);  // == jnp.minimum (no NaNs)
      mind[j] = nm;
      if (nm > bestv) {
        bestv = nm;
        bestj = j;
      }
    }
    int besti = bestj * FPS_T + t;

    // Wave-level argmax reduce, tie -> smaller index.
#pragma unroll
    for (int off = 32; off > 0; off >>= 1) {
      const float ov = __shfl_xor(bestv, off, 64);
      const int oi = __shfl_xor(besti, off, 64);
      if (ov > bestv || (ov == bestv && oi < besti)) {
        bestv = ov;
        besti = oi;
      }
    }
    const int w = t >> 6;
    if ((t & 63) == 0) {
      s_rv[w] = bestv;
      s_ri[w] = besti;
    }
    __syncthreads();
    if (t == 0) {
      float bv = s_rv[0];
      int bi = s_ri[0];
#pragma unroll
      for (int ww = 1; ww < FPS_T / 64; ++ww) {
        const float v = s_rv[ww];
        const int i2 = s_ri[ww];
        if (v > bv || (v == bv && i2 < bi)) {
          bv = v;
          bi = i2;
        }
      }
      s_g = bi;
    }
    __syncthreads();
    g = __builtin_amdgcn_readfirstlane(s_g);  // uniform -> SGPR
  }
}

// ---------------------------------------------------------------------------
// Kernel 2: radius-neighbor capped mean (passed R3, ~0.15 ms). One wave per
// 4 centers; membership in op-by-op f32; sums f32. count>64: exact ordered
// first-64 re-scan (wave-uniform, rare).
// ---------------------------------------------------------------------------
#define K2_T 256
__global__ __launch_bounds__(K2_T, 4) void nbr_kernel(
    const float* __restrict__ x, const float* __restrict__ pos,
    float* __restrict__ out) {
  const int lane = threadIdx.x & 63;
  const int w = threadIdx.x >> 6;
  const int cbase = blockIdx.x * 16 + w * 4;  // 4 centers per wave

  const int* idx_stash = (const int*)(out + (size_t)2 * BATCH * M * 3);
  float* out_x = out;
  float* out_batch = out + (size_t)2 * BATCH * M * 3;

  const int b = cbase / M;  // all 16 centers of a block share a cloud
  const float* xb = x + (size_t)b * NPTS * 3;
  const float* pb = pos + (size_t)b * NPTS * 3;

  float cc0[4], cc1[4], cc2[4], cc3[4], cc4[4], cc5[4];
#pragma unroll
  for (int i = 0; i < 4; ++i) {
    const int c = idx_stash[cbase + i];  // local index within cloud
    cc0[i] = xb[3 * c + 0];
    cc1[i] = xb[3 * c + 1];
    cc2[i] = xb[3 * c + 2];
    cc3[i] = pb[3 * c + 0];
    cc4[i] = pb[3 * c + 1];
    cc5[i] = pb[3 * c + 2];
  }

  float s0[4] = {0, 0, 0, 0}, s1[4] = {0, 0, 0, 0}, s2[4] = {0, 0, 0, 0};
  int cnt[4] = {0, 0, 0, 0};

  for (int p = lane; p < NPTS; p += 64) {
    const float x0 = xb[3 * p + 0];
    const float x1 = xb[3 * p + 1];
    const float x2 = xb[3 * p + 2];
    const float q0 = pb[3 * p + 0];
    const float q1 = pb[3 * p + 1];
    const float q2 = pb[3 * p + 2];
#pragma unroll
    for (int i = 0; i < 4; ++i) {
      const float d2 = dist2_seq(cc0[i], cc1[i], cc2[i], cc3[i], cc4[i],
                                 cc5[i], x0, x1, x2, q0, q1, q2);
      if (d2 <= R2F) {
        cnt[i] += 1;
        s0[i] += x0;
        s1[i] += x1;
        s2[i] += x2;
      }
    }
  }

#pragma unroll
  for (int i = 0; i < 4; ++i) {
#pragma unroll
    for (int off = 32; off > 0; off >>= 1) {
      s0[i] += __shfl_xor(s0[i], off, 64);
      s1[i] += __shfl_xor(s1[i], off, 64);
      s2[i] += __shfl_xor(s2[i], off, 64);
      cnt[i] += __shfl_xor(cnt[i], off, 64);
    }
  }

#pragma unroll
  for (int i = 0; i < 4; ++i) {
    const int total = cnt[i];
    float m0, m1, m2;
    if (total <= MAX_NB) {
      const float denom = (float)total;  // >= 1 (self is always in range)
      m0 = s0[i] / denom;
      m1 = s1[i] / denom;
      m2 = s2[i] / denom;
    } else {
      // Exact first-64-by-index fallback (wave-uniform branch, rare).
      const int base = lane * (NPTS / 64);
      int lc = 0;
      for (int p = base; p < base + NPTS / 64; ++p) {
        const float d2 =
            dist2_seq(cc0[i], cc1[i], cc2[i], cc3[i], cc4[i], cc5[i],
                      xb[3 * p + 0], xb[3 * p + 1], xb[3 * p + 2],
                      pb[3 * p + 0], pb[3 * p + 1], pb[3 * p + 2]);
        if (d2 <= R2F) lc += 1;
      }
      int pre = 0;
      for (int l = 0; l < 64; ++l) {
        const int c = __shfl(lc, l, 64);
        if (l < lane) pre += c;
      }
      float t0 = 0, t1 = 0, t2 = 0;
      int r = pre;
      for (int p = base; p < base + NPTS / 64; ++p) {
        const float x0 = xb[3 * p + 0], x1 = xb[3 * p + 1],
                    x2 = xb[3 * p + 2];
        const float d2 =
            dist2_seq(cc0[i], cc1[i], cc2[i], cc3[i], cc4[i], cc5[i], x0, x1,
                      x2, pb[3 * p + 0], pb[3 * p + 1], pb[3 * p + 2]);
        if (d2 <= R2F) {
          if (r < MAX_NB) {
            t0 += x0;
            t1 += x1;
            t2 += x2;
          }
          r += 1;
        }
      }
#pragma unroll
      for (int off = 32; off > 0; off >>= 1) {
        t0 += __shfl_xor(t0, off, 64);
        t1 += __shfl_xor(t1, off, 64);
        t2 += __shfl_xor(t2, off, 64);
      }
      m0 = t0 / 64.0f;
      m1 = t1 / 64.0f;
      m2 = t2 / 64.0f;
    }
    if (lane == i) {
      const int gc = cbase + i;
      out_x[(size_t)gc * 3 + 0] = m0;
      out_x[(size_t)gc * 3 + 1] = m1;
      out_x[(size_t)gc * 3 + 2] = m2;
      out_batch[gc] = (float)b;  // batch ids as float in the float32 buffer
    }
  }
}

extern "C" void kernel_launch(void* const* d_in, const int* in_sizes, int n_in,
                              void* d_out, int out_size, void* d_ws,
                              size_t ws_size, hipStream_t stream) {
  (void)in_sizes;
  (void)n_in;
  (void)out_size;
  (void)d_ws;
  (void)ws_size;
  const float* x = (const float*)d_in[0];
  const float* pos = (const float*)d_in[1];
  // d_in[2] (batch) is implied by the contiguous equal-size layout.
  float* out = (float*)d_out;

  fps_kernel<<<BATCH, FPS_T, 0, stream>>>(x, pos, out);
  nbr_kernel<<<(BATCH * M) / 16, K2_T, 0, stream>>>(x, pos, out);
}